// Round 11
// baseline (278196.533 us; speedup 1.0000x reference)
//
#include <hip/hip_runtime.h>
#include <math.h>

namespace {

typedef unsigned long long u64;

constexpr int cH  = 1024;
constexpr int cZ  = 256;
constexpr int cB  = 64;
constexpr int cT  = 256;
constexpr int cR  = 389;
constexpr int cSC = 89;
constexpr int cPF = 300;
constexpr int WSTR = 400;               // padded encoder w_ih / x stride (floats) = 100 f4
constexpr float INV_S = 0.9999950000374997f;  // 1/sqrt(1+1e-5)

__device__ __forceinline__ void fma4(float4& a, const float4 x, const float4 w){
  a.x = fmaf(x.x, w.x, a.x);
  a.y = fmaf(x.y, w.y, a.y);
  a.z = fmaf(x.z, w.z, a.z);
  a.w = fmaf(x.w, w.w, a.w);
}
__device__ __forceinline__ float fold4(const float4 a){ return (a.x + a.y) + (a.z + a.w); }
__device__ __forceinline__ float4 z4(){ return make_float4(0.f, 0.f, 0.f, 0.f); }
__device__ __forceinline__ float sigm(float x){ return 1.f / (1.f + expf(-x)); }

// ---- coherent primitives ----
__device__ __forceinline__ void cfence(){ asm volatile("" ::: "memory"); }
__device__ __forceinline__ void ld_cg(float4& d, const float4* p){
  asm volatile("global_load_dwordx4 %0, %1, off sc0 sc1" : "=v"(d) : "v"(p) : "memory");
}
// 128-bit asm *inputs* are unsupported (r10 compile fail) -> two 64-bit atomic stores
__device__ __forceinline__ void st_cg(float4* p, float4 v){
  union { float4 f; u64 u[2]; } c; c.f = v;
  u64* q = (u64*)p;
  __hip_atomic_store(q,     c.u[0], __ATOMIC_RELAXED, __HIP_MEMORY_SCOPE_AGENT);
  __hip_atomic_store(q + 1, c.u[1], __ATOMIC_RELAXED, __HIP_MEMORY_SCOPE_AGENT);
}
__device__ __forceinline__ void vm_drain(){
  asm volatile("s_waitcnt vmcnt(0)" ::: "memory");
  __builtin_amdgcn_sched_barrier(0);
}
__device__ __forceinline__ void st_scal(float* p, float v){
  __hip_atomic_store(p, v, __ATOMIC_RELAXED, __HIP_MEMORY_SCOPE_AGENT);
}

// ---- single-level 8-block group barrier; RELEASE arrival orders prior stores ----
// layout (uint slots): cnt at [0], gen at [32]
__device__ __forceinline__ void gbar8(unsigned* base){
  __syncthreads();
  if (threadIdx.x == 0){
    cfence();
    const unsigned g = __hip_atomic_load(base + 32, __ATOMIC_RELAXED, __HIP_MEMORY_SCOPE_AGENT);
    const unsigned a = __hip_atomic_fetch_add(base, 1u,
                         __ATOMIC_RELEASE, __HIP_MEMORY_SCOPE_AGENT);
    if (a == 7u){
      __hip_atomic_store(base, 0u, __ATOMIC_RELAXED, __HIP_MEMORY_SCOPE_AGENT);
      __hip_atomic_store(base + 32, g + 1u, __ATOMIC_RELEASE, __HIP_MEMORY_SCOPE_AGENT);
    } else {
      while (__hip_atomic_load(base + 32, __ATOMIC_RELAXED, __HIP_MEMORY_SCOPE_AGENT) == g)
        __builtin_amdgcn_s_sleep(1);
    }
    cfence();
  }
  __syncthreads();
}

// ---------------------------------------------------------------- prep kernels
__global__ __launch_bounds__(256) void init_kernel(float* hf0, float* hb0, float* dout_tail,
                                                   unsigned* barE, unsigned* barD){
  const int idx = blockIdx.x * 256 + threadIdx.x;
  const int stride = gridDim.x * 256;
  for (int i = idx; i < cB * cH; i += stride){ hf0[i] = 0.f; hb0[i] = 0.f; }
  for (int i = idx; i < 2 * cB * cZ; i += stride) dout_tail[i] = 0.f;
  for (int i = idx; i < 4096; i += stride){ barE[i] = 0u; barD[i] = 0u; }
}

__global__ __launch_bounds__(256) void pad_wih_kernel(const float* __restrict__ w,
                                                      float* __restrict__ wp){
  const int idx = blockIdx.x * 256 + threadIdx.x;
  const int stride = gridDim.x * 256;
  const int n = 3 * cH * WSTR;
  for (int i = idx; i < n; i += stride){
    const int r = i / WSTR, c = i - r * WSTR;
    wp[i] = (c < cR) ? w[(size_t)r * cR + c] : 0.f;
  }
}

__global__ __launch_bounds__(256) void pad_x_kernel(const float* __restrict__ x,
                                                    float* __restrict__ xp){
  const int idx = blockIdx.x * 256 + threadIdx.x;
  const int stride = gridDim.x * 256;
  const int n = cT * cB * WSTR;
  for (int i = idx; i < n; i += stride){
    const int r = i / WSTR, c = i - r * WSTR;
    xp[i] = (c < cR) ? x[(size_t)r * cR + c] : 0.f;
  }
}

__global__ __launch_bounds__(256) void pad_wsc_kernel(const float* __restrict__ w_ih0,
                                                      float* __restrict__ wsc){
  const int idx = blockIdx.x * 256 + threadIdx.x;
  const int stride = gridDim.x * 256;
  const int n = 3 * cH * 96;
  for (int i = idx; i < n; i += stride){
    const int r = i / 96, c = i - r * 96;
    wsc[i] = (c < cSC) ? w_ih0[(size_t)r * 645 + 300 + c] : 0.f;
  }
}

// transposed one-hot block of w_ih0: wpfT[c * 3072 + gk] = w_ih0[gk][c] for c < 300
__global__ __launch_bounds__(256) void trans_wpf_kernel(const float* __restrict__ w,
                                                        float* __restrict__ wt){
  const int idx = blockIdx.x * 256 + threadIdx.x;
  const int stride = gridDim.x * 256;
  const int n = cPF * 3 * cH;
  for (int i = idx; i < n; i += stride){
    const int c = i / (3 * cH), r = i - c * (3 * cH);
    wt[i] = w[(size_t)r * 645 + c];
  }
}

// ---------------------------------------------------------------- encoder (persistent)
// 512 blocks: kq = bid&7 (128 k-rows), slot = bid>>3: dir = slot>>5, bg = slot&31 (2 batches).
// threads 512: row = tid>>2 (128), bloc = (tid>>1)&1, half = tid&1.
__global__ __launch_bounds__(512, 4) void enc_persist(
    const float* __restrict__ xp,
    const float* __restrict__ wihPf, const float* __restrict__ whh_f,
    const float* __restrict__ bih_f, const float* __restrict__ bhh_f,
    const float* __restrict__ wihPb, const float* __restrict__ whh_b,
    const float* __restrict__ bih_b, const float* __restrict__ bhh_b,
    float* __restrict__ hfA, float* __restrict__ hfB,
    float* __restrict__ hbA, float* __restrict__ hbB,
    unsigned* __restrict__ barE)
{
  const int bid  = blockIdx.x;
  const int kq   = bid & 7;
  const int slot = bid >> 3;
  const int dir  = slot >> 5;
  const int bg   = slot & 31;
  unsigned* bar  = barE + (dir * 32 + bg) * 64;

  const float* wih = dir ? wihPb : wihPf;
  const float* whh = dir ? whh_b : whh_f;
  const float* bih = dir ? bih_b : bih_f;
  const float* bhh = dir ? bhh_b : bhh_f;
  float* bufA = dir ? hbA : hfA;
  float* bufB = dir ? hbB : hfB;

  const int tid   = threadIdx.x;
  const int row   = tid >> 2;
  const int bloc  = (tid >> 1) & 1;
  const int half  = tid & 1;
  const int kbase = kq * 128;
  const int bbase = bg * 2;
  const int k     = kbase + row;

  __shared__ alignas(16) float arena[2 * 1028];
  __shared__ alignas(16) float harena[256];
  float4* stg4 = (float4*)arena;
  float4* harena4 = (float4*)harena;

  const float4* wi0 = (const float4*)wih + (size_t)k * 100;
  const float4* wi1 = (const float4*)wih + (size_t)(cH + k) * 100;
  const float4* wi2 = (const float4*)wih + (size_t)(2*cH + k) * 100;
  const float4* wh0 = (const float4*)whh + (size_t)k * 256;
  const float4* wh1 = (const float4*)whh + (size_t)(cH + k) * 256;
  const float4* wh2 = (const float4*)whh + (size_t)(2*cH + k) * 256;
  const float4* xp4 = (const float4*)xp;

  for (int t = 0; t < cT; ++t){
    const float* hin = (t & 1) ? bufB : bufA;
    float*      hout = (t & 1) ? bufA : bufB;
    const int tt = dir ? (cT - 1 - t) : t;

    {
      const int bsel = tid >> 8, col = tid & 255;
      float4 v;
      ld_cg(v, (const float4*)hin + (size_t)(bbase + bsel) * 256 + col);
      vm_drain();
      stg4[bsel * 257 + col] = v;
    }
    __syncthreads();

    float4 R = z4(), Z = z4(), NI = z4(), NH = z4();
    {
      const float4* xr = xp4 + (size_t)(tt * cB + bbase + bloc) * 100;
      #pragma unroll 5
      for (int c = 0; c < 50; ++c){
        const int cc = half * 50 + c;
        const float4 a = xr[cc];
        fma4(R, a, wi0[cc]); fma4(Z, a, wi1[cc]); fma4(NI, a, wi2[cc]);
      }
    }
    #pragma unroll 4
    for (int c = 0; c < 128; ++c){
      const int cc = half * 128 + c;
      const float4 a = stg4[bloc * 257 + cc];
      fma4(R, a, wh0[cc]); fma4(Z, a, wh1[cc]); fma4(NH, a, wh2[cc]);
    }
    float rs = fold4(R), zs = fold4(Z), nis = fold4(NI), nhs = fold4(NH);
    rs  += __shfl_xor(rs, 1);
    zs  += __shfl_xor(zs, 1);
    nis += __shfl_xor(nis, 1);
    nhs += __shfl_xor(nhs, 1);
    if (half == 0){
      const float r  = sigm(rs + bih[k] + bhh[k]);
      const float zg = sigm(zs + bih[cH + k] + bhh[cH + k]);
      const float nn = tanhf(nis + bih[2*cH + k] + r * (nhs + bhh[2*cH + k]));
      const float hp = arena[bloc * 1028 + k];
      harena[bloc * 128 + row] = (1.f - zg) * nn + zg * hp;
    }
    __syncthreads();
    if (tid < 64){
      const int b2 = tid >> 5, i = tid & 31;
      st_cg((float4*)hout + (size_t)(bbase + b2) * 256 + kq * 32 + i,
            harena4[b2 * 32 + i]);
    }
    gbar8(bar);
  }
}

// ---------------------------------------------------------------- decoder (persistent)
// 512 blocks: kq = bid&7 (128 k-rows), batch = bid>>3.  Per-batch barrier domain of 8.
// threads 512: row = tid>>2 (128), quad = tid&3 (4 col-segs of 64 f4).
__global__ __launch_bounds__(512, 4) void dec_persist(
    const float* __restrict__ x,
    const float* __restrict__ hfA, const float* __restrict__ hbA,
    const float* __restrict__ w_mu, const float* __restrict__ b_mu,
    const float* __restrict__ w_init, const float* __restrict__ b_init,
    const float* __restrict__ w_ih0,  const float* __restrict__ wpfT,
    const float* __restrict__ wsc,   const float* __restrict__ w_hh0,
    const float* __restrict__ b_ih0, const float* __restrict__ b_hh0,
    const float* __restrict__ w_ih1, const float* __restrict__ w_hh1,
    const float* __restrict__ b_ih1, const float* __restrict__ b_hh1,
    const float* __restrict__ w_ih2, const float* __restrict__ w_hh2,
    const float* __restrict__ b_ih2, const float* __restrict__ b_hh2,
    const float* __restrict__ w_out, const float* __restrict__ b_out,
    float* __restrict__ h0A, float* __restrict__ h0B,
    float* __restrict__ h1A, float* __restrict__ h1B,
    float* __restrict__ h2A, float* __restrict__ h2B,
    float* __restrict__ zbuf, float* __restrict__ lgbuf,
    float* __restrict__ dout,
    unsigned* __restrict__ barD)
{
  const int bid   = blockIdx.x;
  const int kq    = bid & 7;
  const int batch = bid >> 3;
  const int kbase = kq * 128;
  unsigned* bar   = barD + batch * 64;
  const int tid   = threadIdx.x;
  const int row   = tid >> 2;
  const int quad  = tid & 3;
  const int k     = kbase + row;

  __shared__ alignas(16) float arena[2 * 1028];   // stage buf0/buf1; lgar overlays buf1
  __shared__ alignas(16) float harena[128];
  __shared__ alignas(16) float scs[100];
  __shared__ float gz[3][128];
  __shared__ float gm[3], gl[3];
  __shared__ int   amsI;

  float4* stg4 = (float4*)arena;
  float4* harena4 = (float4*)harena;
  const float4* scs4 = (const float4*)scs;
  float* lgar = arena + 1028;
  float4* lgar4 = (float4*)lgar;
  const float4* wsc4 = (const float4*)wsc;
  const float4* wout4 = (const float4*)w_out;

  auto fold = [&](int jm1, bool writeAms){
    {
      float4 v = z4();
      if (tid < 75) ld_cg(v, (const float4*)lgbuf + (size_t)batch * 75 + tid);
      vm_drain();
      if (tid < 75) lgar4[tid] = v;
    }
    __syncthreads();
    if (tid < 64){
      #pragma unroll
      for (int g3 = 0; g3 < 3; ++g3){
        const int base = g3 * 100;
        float mm = fmaxf(lgar[base + tid], (tid < 36) ? lgar[base + 64 + tid] : -INFINITY);
        #pragma unroll
        for (int off = 32; off > 0; off >>= 1) mm = fmaxf(mm, __shfl_xor(mm, off));
        float ss = expf(lgar[base + tid] - mm)
                 + ((tid < 36) ? expf(lgar[base + 64 + tid] - mm) : 0.f);
        #pragma unroll
        for (int off = 32; off > 0; off >>= 1) ss += __shfl_xor(ss, off);
        if (tid == 0){ gm[g3] = mm; gl[g3] = logf(ss); }
      }
    }
    __syncthreads();
    if (tid < cPF){
      const int g3 = (tid >= 200) ? 2 : ((tid >= 100) ? 1 : 0);
      const float o = lgar[tid] - gm[g3] - gl[g3];
      if (kq == 0) dout[((size_t)batch * cT + jm1) * cPF + tid] = o;
      lgar[tid] = o;
    }
    __syncthreads();
    if (writeAms && tid < 64){
      float best = -INFINITY; int bi = 0x7fffffff;
      #pragma unroll
      for (int kk = 0; kk < 5; ++kk){
        const int p = tid + 64 * kk;
        if (p < cPF){
          const float o = lgar[p];
          if (o > best || (o == best && p < bi)){ best = o; bi = p; }
        }
      }
      #pragma unroll
      for (int off = 32; off > 0; off >>= 1){
        const float ob = __shfl_xor(best, off);
        const int   oi = __shfl_xor(bi, off);
        if (ob > best || (ob == best && oi < bi)){ best = ob; bi = oi; }
      }
      if (tid == 0) amsI = bi;
    }
    __syncthreads();
  };

  auto layerBC = [&](const float* inG, const float* pvG,
                     const float* wih, const float* whh,
                     const float* bi, const float* bhv, float* outG){
    {
      const int bsel = tid >> 8, col = tid & 255;
      const float4* src = (const float4*)(bsel ? pvG : inG) + (size_t)batch * 256 + col;
      float4 v; ld_cg(v, src);
      vm_drain();
      stg4[bsel * 257 + col] = v;
    }
    __syncthreads();
    const float4* wi0 = (const float4*)wih + (size_t)k * 256;
    const float4* wi1 = (const float4*)wih + (size_t)(cH + k) * 256;
    const float4* wi2 = (const float4*)wih + (size_t)(2*cH + k) * 256;
    const float4* wh0 = (const float4*)whh + (size_t)k * 256;
    const float4* wh1 = (const float4*)whh + (size_t)(cH + k) * 256;
    const float4* wh2 = (const float4*)whh + (size_t)(2*cH + k) * 256;
    float4 R = z4(), Z = z4(), NI = z4(), NH = z4();
    #pragma unroll 4
    for (int c = 0; c < 64; ++c){
      const int cc = quad * 64 + c;
      const float4 ai = stg4[cc];
      const float4 ah = stg4[257 + cc];
      fma4(R, ai, wi0[cc]); fma4(Z, ai, wi1[cc]); fma4(NI, ai, wi2[cc]);
      fma4(R, ah, wh0[cc]); fma4(Z, ah, wh1[cc]); fma4(NH, ah, wh2[cc]);
    }
    float rs = fold4(R), zs = fold4(Z), nis = fold4(NI), nhs = fold4(NH);
    rs  += __shfl_xor(rs, 1);  rs  += __shfl_xor(rs, 2);
    zs  += __shfl_xor(zs, 1);  zs  += __shfl_xor(zs, 2);
    nis += __shfl_xor(nis, 1); nis += __shfl_xor(nis, 2);
    nhs += __shfl_xor(nhs, 1); nhs += __shfl_xor(nhs, 2);
    if (quad == 0){
      const float r  = sigm(rs + bi[k] + bhv[k]);
      const float zg = sigm(zs + bi[cH + k] + bhv[cH + k]);
      const float nn = tanhf(nis + bi[2*cH + k] + r * (nhs + bhv[2*cH + k]));
      const float hp = arena[1028 + k];
      harena[row] = (1.f - zg) * nn + zg * hp;
    }
    __syncthreads();
    if (tid < 32)
      st_cg((float4*)outG + (size_t)batch * 256 + kq * 32 + tid, harena4[tid]);
  };

  // ================= prologue: latent z =================
  {
    float4* hl4 = (float4*)arena;
    hl4[tid] = (tid < 256) ? ((const float4*)hfA)[(size_t)batch * 256 + tid]
                           : ((const float4*)hbA)[(size_t)batch * 256 + (tid - 256)];
    __syncthreads();
    const int i = tid >> 4, l16 = tid & 15;
    const int c = kq * 32 + i;
    const float4* wr = (const float4*)w_mu + (size_t)c * 512;
    float4 s = z4();
    #pragma unroll 4
    for (int u = 0; u < 32; ++u){
      const int d = l16 * 32 + u;
      fma4(s, hl4[d], wr[d]);
    }
    float v = fold4(s);
    v += __shfl_xor(v, 1); v += __shfl_xor(v, 2);
    v += __shfl_xor(v, 4); v += __shfl_xor(v, 8);
    if (l16 == 0) harena[i] = b_mu[c] + v * INV_S;
    __syncthreads();
    if (tid < 8)
      st_cg((float4*)zbuf + (size_t)batch * 64 + kq * 8 + tid, harena4[tid]);
  }
  gbar8(bar);
  {
    // stage full z (256 floats) into arena; then gz (layer0 z-part) + hinit
    {
      float4 v = z4();
      if (tid < 64) ld_cg(v, (const float4*)zbuf + (size_t)batch * 64 + tid);
      vm_drain();
      if (tid < 64) ((float4*)arena)[tid] = v;
    }
    __syncthreads();
    if (tid < 384){
      const int g = tid >> 7, r = tid & 127;
      const float* wrow = w_ih0 + (size_t)(g * cH + kbase + r) * 645 + 389;
      float s = 0.f;
      #pragma unroll 4
      for (int d = 0; d < cZ; ++d) s = fmaf(arena[d], wrow[d], s);
      gz[g][r] = s;
    }
    __syncthreads();
    {
      const float4* zl4 = (const float4*)arena;
      const float4* wr4 = (const float4*)w_init + (size_t)k * 64;
      float4 s = z4();
      #pragma unroll 4
      for (int u = 0; u < 16; ++u){
        const int d = quad * 16 + u;
        fma4(s, zl4[d], wr4[d]);
      }
      float v = fold4(s);
      v += __shfl_xor(v, 1); v += __shfl_xor(v, 2);
      if (quad == 0) harena[row] = tanhf(b_init[k] + v);
    }
    __syncthreads();
    if (tid < 32)
      st_cg((float4*)h0A + (size_t)batch * 256 + kq * 32 + tid, harena4[tid]);
  }
  gbar8(bar);

  // ================= main loop =================
  for (int j = 0; j < cT; ++j){
    const int par = j & 1;
    const float* h0p = par ? h0B : h0A;  float* h0n = par ? h0A : h0B;
    const float* h1p = par ? h1B : h1A;  float* h1n = par ? h1A : h1B;
    const float* h2p = par ? h2B : h2A;  float* h2n = par ? h2A : h2B;

    // ---- phase A: fold(prev) + layer 0
    {
      if (j == 0){
        if (tid == 0) amsI = cPF - 1;
        if (tid < 96) scs[tid] = (tid == cSC - 1) ? 1.f : 0.f;
      } else {
        fold(j - 1, true);
        if (tid < 96)
          scs[tid] = (tid < cSC) ? x[((size_t)(j - 1) * cB + batch) * cR + tid] : 0.f;
      }
      __syncthreads();
      {
        float4 v = z4();
        if (tid < 256) ld_cg(v, (const float4*)h0p + (size_t)batch * 256 + tid);
        vm_drain();
        if (tid < 256) stg4[tid] = v;
      }
      __syncthreads();

      const float4* ws0 = wsc4 + (size_t)k * 24;
      const float4* ws1 = wsc4 + (size_t)(cH + k) * 24;
      const float4* ws2 = wsc4 + (size_t)(2*cH + k) * 24;
      const float4* wh0 = (const float4*)w_hh0 + (size_t)k * 256;
      const float4* wh1 = (const float4*)w_hh0 + (size_t)(cH + k) * 256;
      const float4* wh2 = (const float4*)w_hh0 + (size_t)(2*cH + k) * 256;
      float4 R = z4(), Z = z4(), NI = z4(), NH = z4();
      #pragma unroll
      for (int c = 0; c < 6; ++c){
        const int cc = quad * 6 + c;
        const float4 a = scs4[cc];
        fma4(R, a, ws0[cc]); fma4(Z, a, ws1[cc]); fma4(NI, a, ws2[cc]);
      }
      #pragma unroll 4
      for (int c = 0; c < 64; ++c){
        const int cc = quad * 64 + c;
        const float4 a = stg4[cc];
        fma4(R, a, wh0[cc]); fma4(Z, a, wh1[cc]); fma4(NH, a, wh2[cc]);
      }
      float rs = fold4(R), zs = fold4(Z), nis = fold4(NI), nhs = fold4(NH);
      rs  += __shfl_xor(rs, 1);  rs  += __shfl_xor(rs, 2);
      zs  += __shfl_xor(zs, 1);  zs  += __shfl_xor(zs, 2);
      nis += __shfl_xor(nis, 1); nis += __shfl_xor(nis, 2);
      nhs += __shfl_xor(nhs, 1); nhs += __shfl_xor(nhs, 2);
      if (quad == 0){
        const int am = amsI;
        rs  += wpfT[(size_t)am * (3*cH) + k]        + gz[0][row];
        zs  += wpfT[(size_t)am * (3*cH) + cH + k]   + gz[1][row];
        nis += wpfT[(size_t)am * (3*cH) + 2*cH + k] + gz[2][row];
        const float r  = sigm(rs + b_ih0[k] + b_hh0[k]);
        const float zg = sigm(zs + b_ih0[cH + k] + b_hh0[cH + k]);
        const float nn = tanhf(nis + b_ih0[2*cH + k] + r * (nhs + b_hh0[2*cH + k]));
        const float hp = arena[k];
        harena[row] = (1.f - zg) * nn + zg * hp;
      }
      __syncthreads();
      if (tid < 32)
        st_cg((float4*)h0n + (size_t)batch * 256 + kq * 32 + tid, harena4[tid]);
    }
    gbar8(bar);

    layerBC(h0n, (j == 0 ? h0n : h1p), w_ih1, w_hh1, b_ih1, b_hh1, h1n);
    gbar8(bar);
    layerBC(h1n, (j == 0 ? h1n : h2p), w_ih2, w_hh2, b_ih2, b_hh2, h2n);
    gbar8(bar);

    // ---- phase D: logits slice -> lgbuf
    {
      {
        float4 v = z4();
        if (tid < 256) ld_cg(v, (const float4*)h2n + (size_t)batch * 256 + tid);
        vm_drain();
        if (tid < 256) stg4[tid] = v;
      }
      __syncthreads();
      const int p0 = (kq * cPF) >> 3;
      const int np = (((kq + 1) * cPF) >> 3) - p0;
      const int rr = tid >> 3, l8 = tid & 7;
      if (rr < np){
        const int pr = p0 + rr;
        const float4* wr = wout4 + (size_t)pr * 256;
        float4 s = z4();
        #pragma unroll 4
        for (int u = 0; u < 32; ++u){
          const int cc = l8 * 32 + u;
          fma4(s, stg4[cc], wr[cc]);
        }
        float v = fold4(s);
        v += __shfl_xor(v, 1); v += __shfl_xor(v, 2); v += __shfl_xor(v, 4);
        if (l8 == 0) st_scal(&lgbuf[(size_t)batch * cPF + pr], v + b_out[pr]);
      }
    }
    gbar8(bar);
  }

  if (kq == 0) fold(cT - 1, false);
}

} // namespace

// ---------------------------------------------------------------- host
extern "C" void kernel_launch(void* const* d_in, const int* in_sizes, int n_in,
                              void* d_out, int out_size, void* d_ws, size_t ws_size,
                              hipStream_t stream)
{
  const float* x     = (const float*)d_in[0];
  const float* wih_f = (const float*)d_in[2];
  const float* whh_f = (const float*)d_in[3];
  const float* bih_f = (const float*)d_in[4];
  const float* bhh_f = (const float*)d_in[5];
  const float* wih_b = (const float*)d_in[6];
  const float* whh_b = (const float*)d_in[7];
  const float* bih_b = (const float*)d_in[8];
  const float* bhh_b = (const float*)d_in[9];
  const float* w_mu  = (const float*)d_in[10];
  const float* b_mu  = (const float*)d_in[11];
  const float* w_init= (const float*)d_in[14];
  const float* b_init= (const float*)d_in[15];
  const float* w_ih0 = (const float*)d_in[16];
  const float* w_hh0 = (const float*)d_in[17];
  const float* b_ih0 = (const float*)d_in[18];
  const float* b_hh0 = (const float*)d_in[19];
  const float* w_ih1 = (const float*)d_in[20];
  const float* w_hh1 = (const float*)d_in[21];
  const float* b_ih1 = (const float*)d_in[22];
  const float* b_hh1 = (const float*)d_in[23];
  const float* w_ih2 = (const float*)d_in[24];
  const float* w_hh2 = (const float*)d_in[25];
  const float* b_ih2 = (const float*)d_in[26];
  const float* b_hh2 = (const float*)d_in[27];
  const float* w_out = (const float*)d_in[28];
  const float* b_out = (const float*)d_in[29];
  float* dout = (float*)d_out;

  float* ws = (float*)d_ws;
  float* wihfP = ws; ws += (size_t)3 * cH * WSTR;     // 4.9 MB
  float* wihbP = ws; ws += (size_t)3 * cH * WSTR;     // 4.9 MB
  float* xp    = ws; ws += (size_t)cT * cB * WSTR;    // 26.2 MB
  float* wsc   = ws; ws += (size_t)3 * cH * 96;       // 1.2 MB
  float* wpfT  = ws; ws += (size_t)cPF * 3 * cH;      // 3.7 MB
  float* hfA = ws; ws += cB * cH;  float* hfB = ws; ws += cB * cH;
  float* hbA = ws; ws += cB * cH;  float* hbB = ws; ws += cB * cH;
  float* h0A = ws; ws += cB * cH;  float* h0B = ws; ws += cB * cH;
  float* h1A = ws; ws += cB * cH;  float* h1B = ws; ws += cB * cH;
  float* h2A = ws; ws += cB * cH;  float* h2B = ws; ws += cB * cH;
  float* zbuf  = ws; ws += cB * cZ;
  float* lgbuf = ws; ws += cB * cPF;
  ws = (float*)(((uintptr_t)ws + 255) & ~(uintptr_t)255);
  unsigned* barE = (unsigned*)ws;  ws += 4096;  // 64 domains x 64 uints
  unsigned* barD = (unsigned*)ws;  ws += 4096;  // 64 domains x 64 uints

  init_kernel<<<256, 256, 0, stream>>>(hfA, hbA, dout + (size_t)cB * cT * cPF, barE, barD);
  pad_wih_kernel<<<512, 256, 0, stream>>>(wih_f, wihfP);
  pad_wih_kernel<<<512, 256, 0, stream>>>(wih_b, wihbP);
  pad_x_kernel<<<2048, 256, 0, stream>>>(x, xp);
  pad_wsc_kernel<<<512, 256, 0, stream>>>(w_ih0, wsc);
  trans_wpf_kernel<<<2048, 256, 0, stream>>>(w_ih0, wpfT);

  enc_persist<<<512, 512, 0, stream>>>(
      xp,
      wihfP, whh_f, bih_f, bhh_f,
      wihbP, whh_b, bih_b, bhh_b,
      hfA, hfB, hbA, hbB, barE);

  dec_persist<<<512, 512, 0, stream>>>(
      x, hfA, hbA,
      w_mu, b_mu, w_init, b_init,
      w_ih0, wpfT, wsc, w_hh0, b_ih0, b_hh0,
      w_ih1, w_hh1, b_ih1, b_hh1,
      w_ih2, w_hh2, b_ih2, b_hh2,
      w_out, b_out,
      h0A, h0B, h1A, h1B, h2A, h2B,
      zbuf, lgbuf, dout, barD);
}

// Round 13
// 56439.014 us; speedup vs baseline: 4.9292x; 4.9292x over previous
//
#include <hip/hip_runtime.h>
#include <math.h>

namespace {

typedef unsigned long long u64;

constexpr int cH  = 1024;
constexpr int cZ  = 256;
constexpr int cB  = 64;
constexpr int cT  = 256;
constexpr int cR  = 389;
constexpr int cSC = 89;
constexpr int cPF = 300;
constexpr int WSTR = 400;               // padded encoder w_ih stride (floats) = 100 f4
constexpr float INV_S = 0.9999950000374997f;  // 1/sqrt(1+1e-5)

__device__ __forceinline__ void fma4(float4& a, const float4 x, const float4 w){
  a.x = fmaf(x.x, w.x, a.x);
  a.y = fmaf(x.y, w.y, a.y);
  a.z = fmaf(x.z, w.z, a.z);
  a.w = fmaf(x.w, w.w, a.w);
}
__device__ __forceinline__ float fold4(const float4 a){ return (a.x + a.y) + (a.z + a.w); }
__device__ __forceinline__ float4 z4(){ return make_float4(0.f, 0.f, 0.f, 0.f); }
__device__ __forceinline__ float sigm(float x){ return 1.f / (1.f + expf(-x)); }

// ---- guaranteed-coherent primitives (no inline-asm data movement) ----
__device__ __forceinline__ void cfence(){ asm volatile("" ::: "memory"); }
__device__ __forceinline__ u64 ld_u64(const u64* p){
  return __hip_atomic_load(p, __ATOMIC_RELAXED, __HIP_MEMORY_SCOPE_AGENT);
}
__device__ __forceinline__ float ld_scal(const float* p){
  return __hip_atomic_load(p, __ATOMIC_RELAXED, __HIP_MEMORY_SCOPE_AGENT);
}
__device__ __forceinline__ void st_scal(float* p, float v){
  __hip_atomic_store(p, v, __ATOMIC_RELAXED, __HIP_MEMORY_SCOPE_AGENT);
}

// ---- two-level group barrier; RELEASE arrival orders prior agent stores ----
__device__ __forceinline__ void gbarN(unsigned* base, int sub, unsigned subCnt,
                                      int nsub, unsigned rootCnt){
  __syncthreads();
  if (threadIdx.x == 0){
    cfence();
    unsigned* root = base + nsub * 16;
    unsigned* gen  = base + nsub * 16 + 16;
    const unsigned g = __hip_atomic_load(gen, __ATOMIC_RELAXED, __HIP_MEMORY_SCOPE_AGENT);
    const unsigned a = __hip_atomic_fetch_add(base + sub * 16, 1u,
                         __ATOMIC_RELEASE, __HIP_MEMORY_SCOPE_AGENT);
    bool flip = false;
    if (a == subCnt - 1u){
      const unsigned r = __hip_atomic_fetch_add(root, 1u,
                           __ATOMIC_RELEASE, __HIP_MEMORY_SCOPE_AGENT);
      if (r == rootCnt - 1u){
        for (int t = 0; t < nsub; ++t)
          __hip_atomic_store(base + t * 16, 0u, __ATOMIC_RELAXED, __HIP_MEMORY_SCOPE_AGENT);
        __hip_atomic_store(root, 0u, __ATOMIC_RELAXED, __HIP_MEMORY_SCOPE_AGENT);
        __hip_atomic_store(gen, g + 1u, __ATOMIC_RELEASE, __HIP_MEMORY_SCOPE_AGENT);
        flip = true;
      }
    }
    if (!flip){
      while (__hip_atomic_load(gen, __ATOMIC_RELAXED, __HIP_MEMORY_SCOPE_AGENT) == g)
        __builtin_amdgcn_s_sleep(1);
    }
    cfence();
  }
  __syncthreads();
}

// ---------------------------------------------------------------- prep kernels
__global__ __launch_bounds__(256) void init_kernel(float* hf0, float* hb0, float* dout_tail,
                                                   unsigned* barE, unsigned* barD){
  const int idx = blockIdx.x * 256 + threadIdx.x;
  const int stride = gridDim.x * 256;
  for (int i = idx; i < cB * cH; i += stride){ hf0[i] = 0.f; hb0[i] = 0.f; }
  for (int i = idx; i < 2 * cB * cZ; i += stride) dout_tail[i] = 0.f;
  for (int i = idx; i < 2048; i += stride){ barE[i] = 0u; barD[i] = 0u; }
}

__global__ __launch_bounds__(256) void pad_wih_kernel(const float* __restrict__ w,
                                                      float* __restrict__ wp){
  const int idx = blockIdx.x * 256 + threadIdx.x;
  const int stride = gridDim.x * 256;
  const int n = 3 * cH * WSTR;
  for (int i = idx; i < n; i += stride){
    const int r = i / WSTR, c = i - r * WSTR;
    wp[i] = (c < cR) ? w[(size_t)r * cR + c] : 0.f;
  }
}

__global__ __launch_bounds__(256) void pad_wsc_kernel(const float* __restrict__ w_ih0,
                                                      float* __restrict__ wsc){
  const int idx = blockIdx.x * 256 + threadIdx.x;
  const int stride = gridDim.x * 256;
  const int n = 3 * cH * 96;
  for (int i = idx; i < n; i += stride){
    const int r = i / 96, c = i - r * 96;
    wsc[i] = (c < cSC) ? w_ih0[(size_t)r * 645 + 300 + c] : 0.f;
  }
}

// ---------------------------------------------------------------- encoder (persistent)
// 256 blocks: xcd=bid&7, slot=bid>>3; dir=slot>>4, sub16=slot&15;
// kblk = xcd*8 + (sub16>>1) (16 k-rows), bhalf = sub16&1 (32 batches).
// tid 512: seg8=tid>>6 -> dseg=seg8&3, khalf=seg8>>2; lane: tx=lane&7, ty=lane>>3.
__global__ __launch_bounds__(512, 2) void enc_persist(
    const float* __restrict__ x,
    const float* __restrict__ wihPf, const float* __restrict__ whh_f,
    const float* __restrict__ bih_f, const float* __restrict__ bhh_f,
    const float* __restrict__ wihPb, const float* __restrict__ whh_b,
    const float* __restrict__ bih_b, const float* __restrict__ bhh_b,
    float* __restrict__ hfA, float* __restrict__ hfB,
    float* __restrict__ hbA, float* __restrict__ hbB,
    unsigned* __restrict__ barE)
{
  const int bid   = blockIdx.x;
  const int xcd   = bid & 7;
  const int slot  = bid >> 3;
  const int dir   = slot >> 4;
  const int sub16 = slot & 15;
  const int kblk  = xcd * 8 + (sub16 >> 1);
  const int bhalf = sub16 & 1;
  unsigned* bar   = barE + (dir * 2 + bhalf) * 512;

  const float* wih = dir ? wihPb : wihPf;
  const float* whh = dir ? whh_b : whh_f;
  const float* bih = dir ? bih_b : bih_f;
  const float* bhh = dir ? bhh_b : bhh_f;
  float* bufA = dir ? hbA : hfA;
  float* bufB = dir ? hbB : hfB;

  const int tid   = threadIdx.x;
  const int seg8  = tid >> 6;
  const int dseg  = seg8 & 3;
  const int khalf = seg8 >> 2;
  const int lane  = tid & 63;
  const int tx    = lane & 7;
  const int ty    = lane >> 3;
  const int k0    = kblk * 16;
  const int bbase = bhalf * 32;
  const int kloc  = khalf * 8 + ty;      // 0..15
  const int k     = k0 + kloc;

  __shared__ float part[4][4][16][33];            // 33.8 KB
  __shared__ alignas(16) float sh[32 * 516];      // 66 KB: 32 rows x 129 f4

  const float4* w0i = (const float4*)wih + (size_t)k * 100;
  const float4* w1i = (const float4*)wih + (size_t)(cH + k) * 100;
  const float4* w2i = (const float4*)wih + (size_t)(2*cH + k) * 100;
  const float4* w0h = (const float4*)whh + (size_t)k * 256;
  const float4* w1h = (const float4*)whh + (size_t)(cH + k) * 256;
  const float4* w2h = (const float4*)whh + (size_t)(2*cH + k) * 256;
  float4* sh4 = (float4*)sh;

  u64 S[16];
  auto stage_issue = [&](const float* hin, int p){
    const u64* s8 = (const u64*)hin;
    #pragma unroll
    for (int i = 0; i < 16; ++i){
      const int e = i * 512 + tid;
      S[i] = ld_u64(s8 + (size_t)(bbase + (e >> 8)) * 512 + p * 256 + (e & 255));
    }
    cfence();
  };
  auto stage_commit = [&](){
    u64* d8 = (u64*)sh;
    #pragma unroll
    for (int i = 0; i < 16; ++i){
      const int e = i * 512 + tid;
      d8[(e >> 8) * 258 + (e & 255)] = S[i];
    }
  };

  for (int t = 0; t < cT; ++t){
    const float* hin = (t & 1) ? bufB : bufA;
    float*      hout = (t & 1) ? bufA : bufB;
    const int tt = dir ? (cT - 1 - t) : t;

    float4 R[4], Z[4], NI[4], NH[4];
    #pragma unroll
    for (int jj = 0; jj < 4; ++jj){ R[jj]=z4(); Z[jj]=z4(); NI[jj]=z4(); NH[jj]=z4(); }

    // issue first h-half stage; overlap with x GEMM
    stage_issue(hin, 0);

    // ---- phase 1: x @ w_ih^T (padded f4 weights, clamped scalar x reads)
    {
      const float* xb[4];
      #pragma unroll
      for (int jj = 0; jj < 4; ++jj)
        xb[jj] = x + ((size_t)tt * cB + bbase + tx + 8*jj) * cR;
      const int c0 = dseg * 25;
      const int cEnd = c0 + 25;
      const int cSafe = (cEnd < 97) ? cEnd : 97;
      for (int c = c0; c < cSafe; ++c){
        const float4 w0v = w0i[c], w1v = w1i[c], w2v = w2i[c];
        const int d = 4 * c;
        #pragma unroll
        for (int jj = 0; jj < 4; ++jj){
          const float* xr = xb[jj];
          const float4 a = make_float4(xr[d], xr[d+1], xr[d+2], xr[d+3]);
          fma4(R[jj], a, w0v); fma4(Z[jj], a, w1v); fma4(NI[jj], a, w2v);
        }
      }
      for (int c = cSafe; c < cEnd; ++c){
        const float4 w0v = w0i[c], w1v = w1i[c], w2v = w2i[c];
        const int d = 4 * c;
        #pragma unroll
        for (int jj = 0; jj < 4; ++jj){
          const float* xr = xb[jj];
          const float4 a = make_float4(
              (d   < cR) ? xr[d]   : 0.f, (d+1 < cR) ? xr[d+1] : 0.f,
              (d+2 < cR) ? xr[d+2] : 0.f, (d+3 < cR) ? xr[d+3] : 0.f);
          fma4(R[jj], a, w0v); fma4(Z[jj], a, w1v); fma4(NI[jj], a, w2v);
        }
      }
    }

    // ---- phase 2: h @ w_hh^T, two halves, pipelined
    stage_commit();
    __syncthreads();
    stage_issue(hin, 1);
    {
      const float4* wp0 = w0h;
      const float4* wp1 = w1h;
      const float4* wp2 = w2h;
      #pragma unroll 4
      for (int c = 0; c < 32; ++c){
        const int cc = dseg * 32 + c;
        const float4 w0v = wp0[cc], w1v = wp1[cc], w2v = wp2[cc];
        #pragma unroll
        for (int jj = 0; jj < 4; ++jj){
          const float4 a = sh4[(tx + 8*jj)*129 + cc];
          fma4(R[jj], a, w0v); fma4(Z[jj], a, w1v); fma4(NH[jj], a, w2v);
        }
      }
    }
    __syncthreads();
    stage_commit();
    __syncthreads();
    {
      const float4* wp0 = w0h + 128;
      const float4* wp1 = w1h + 128;
      const float4* wp2 = w2h + 128;
      #pragma unroll 4
      for (int c = 0; c < 32; ++c){
        const int cc = dseg * 32 + c;
        const float4 w0v = wp0[cc], w1v = wp1[cc], w2v = wp2[cc];
        #pragma unroll
        for (int jj = 0; jj < 4; ++jj){
          const float4 a = sh4[(tx + 8*jj)*129 + cc];
          fma4(R[jj], a, w0v); fma4(Z[jj], a, w1v); fma4(NH[jj], a, w2v);
        }
      }
    }
    __syncthreads();

    #pragma unroll
    for (int jj = 0; jj < 4; ++jj){
      const int b = tx + 8*jj;
      part[dseg][0][kloc][b] = fold4(R[jj]);
      part[dseg][1][kloc][b] = fold4(Z[jj]);
      part[dseg][2][kloc][b] = fold4(NI[jj]);
      part[dseg][3][kloc][b] = fold4(NH[jj]);
    }
    __syncthreads();
    {
      const int row = tid >> 5, bb = tid & 31;   // 16 x 32 = 512 outputs
      float rs=0.f, zs=0.f, nis=0.f, nhs=0.f;
      #pragma unroll
      for (int s = 0; s < 4; ++s){
        rs += part[s][0][row][bb]; zs += part[s][1][row][bb];
        nis += part[s][2][row][bb]; nhs += part[s][3][row][bb];
      }
      const int kk = k0 + row, gb = bbase + bb;
      const float r  = sigm(rs + bih[kk] + bhh[kk]);
      const float zg = sigm(zs + bih[cH + kk] + bhh[cH + kk]);
      const float nn = tanhf(nis + bih[2*cH + kk] + r * (nhs + bhh[2*cH + kk]));
      const float hp = ld_scal(&hin[(size_t)gb * cH + kk]);
      st_scal(&hout[(size_t)gb * cH + kk], (1.f - zg) * nn + zg * hp);
    }
    gbarN(bar, kblk >> 3, 8u, 8, 8u);
  }
}

// ---------------------------------------------------------------- decoder (persistent)
// 256 blocks, XCD-swizzled: xcd=bid&7, slot=bid>>3; kq = xcd*16 + (slot>>1) (8 k-rows),
// bh = slot&1 (32 batches).  Prologue barrier: 256-block domain; loop: per-bh 128.
// tid 512: seg=tid>>6 (d-split 8); lane: ty=lane>>3 (k-row), tx=lane&7; b = tx + 8*jj.
__global__ __launch_bounds__(512, 2) void dec_persist(
    const float* __restrict__ x,
    const float* __restrict__ hfA, const float* __restrict__ hbA,
    const float* __restrict__ w_mu, const float* __restrict__ b_mu,
    const float* __restrict__ w_init, const float* __restrict__ b_init,
    const float* __restrict__ w_ih0,
    const float* __restrict__ wsc,   const float* __restrict__ w_hh0,
    const float* __restrict__ b_ih0, const float* __restrict__ b_hh0,
    const float* __restrict__ w_ih1, const float* __restrict__ w_hh1,
    const float* __restrict__ b_ih1, const float* __restrict__ b_hh1,
    const float* __restrict__ w_ih2, const float* __restrict__ w_hh2,
    const float* __restrict__ b_ih2, const float* __restrict__ b_hh2,
    const float* __restrict__ w_out, const float* __restrict__ b_out,
    float* __restrict__ h0A, float* __restrict__ h0B,
    float* __restrict__ h1A, float* __restrict__ h1B,
    float* __restrict__ h2A, float* __restrict__ h2B,
    float* __restrict__ gi0z, float* __restrict__ zbuf,
    float* __restrict__ amg,  float* __restrict__ scg,
    float* __restrict__ dout,
    unsigned* __restrict__ barD)
{
  const int bid  = blockIdx.x;
  const int xcd  = bid & 7;
  const int slot = bid >> 3;
  const int kq   = xcd * 16 + (slot >> 1);
  const int bh   = slot & 1;
  const int kbase = kq * 8;
  const int bbase = bh * 32;
  const int tid = threadIdx.x;

  const int seg  = tid >> 6;
  const int lane = tid & 63;
  const int tx   = lane & 7;
  const int ty   = lane >> 3;
  const int k    = kbase + ty;

  __shared__ float part[8][4][8][33];              // 33.8 KB
  __shared__ alignas(16) float stg[16 * 1028];     // 65.8 KB (16 rows x 257 f4)
  __shared__ alignas(16) float scs[32 * 100];      // 12.8 KB
  __shared__ float ams[32];
  __shared__ alignas(16) float hb2[cH];            // 4 KB (fold)
  __shared__ float lg[cPF];
  __shared__ float gmax[3], glse[3], wbest[8];
  __shared__ int   wbidx[8];

  float4* stg4 = (float4*)stg;

  #define GBD  gbarN(barD, bid >> 4, 16u, 16, 16u)
  unsigned* barL = barD + 512 + bh * 512;
  #define GBL  gbarN(barL, kq >> 4, 16u, 8, 8u)

  u64 S[16];
  auto stage_issue = [&](const float* src, int gb0){
    const u64* s8 = (const u64*)src;
    #pragma unroll
    for (int i = 0; i < 16; ++i){
      const int e = i * 512 + tid;
      S[i] = ld_u64(s8 + (size_t)(gb0 + (e >> 9)) * 512 + (e & 511));
    }
    cfence();
  };
  auto stage_commit = [&](){
    u64* d8 = (u64*)stg;
    #pragma unroll
    for (int i = 0; i < 16; ++i){
      const int e = i * 512 + tid;
      d8[(e >> 9) * 514 + (e & 511)] = S[i];
    }
  };

  // accumulate stage rows tx and tx+8 over cols seg*32..+32
  auto accH = [&](const float4* w0, const float4* w1, const float4* w2,
                  float4& A0, float4& A1, float4& B0, float4& B1,
                  float4& C0, float4& C1){
    #pragma unroll 4
    for (int c = 0; c < 32; ++c){
      const int cc = seg * 32 + c;
      const float4 w0v = w0[cc], w1v = w1[cc], w2v = w2[cc];
      const float4 aA = stg4[tx * 257 + cc];
      const float4 aB = stg4[(tx + 8) * 257 + cc];
      fma4(A0, aA, w0v); fma4(B0, aA, w1v); fma4(C0, aA, w2v);
      fma4(A1, aB, w0v); fma4(B1, aB, w1v); fma4(C1, aB, w2v);
    }
  };

  auto reduce_store = [&](const float* bi, const float* bhv,
                          const float* hprev, float* hout){
    __syncthreads();
    if (tid < 256){
      const int row = tid >> 5, b = tid & 31;
      float rs=0.f, zs=0.f, nis=0.f, nhs=0.f;
      #pragma unroll
      for (int s = 0; s < 8; ++s){
        rs += part[s][0][row][b]; zs += part[s][1][row][b];
        nis += part[s][2][row][b]; nhs += part[s][3][row][b];
      }
      const int kk = kbase + row, gb = bbase + b;
      const float r  = sigm(rs + bi[kk] + bhv[kk]);
      const float zg = sigm(zs + bi[cH + kk] + bhv[cH + kk]);
      const float nn = tanhf(nis + bi[2*cH + kk] + r * (nhs + bhv[2*cH + kk]));
      const float hp = ld_scal(&hprev[(size_t)gb * cH + kk]);
      st_scal(&hout[(size_t)gb * cH + kk], (1.f - zg) * nn + zg * hp);
    }
  };

  // ================= prologue =================
  if (bid < cB){
    const int b = bid;
    float4* hl4 = (float4*)stg;
    hl4[tid] = (tid < 256) ? ((const float4*)hfA)[(size_t)b * 256 + tid]
                           : ((const float4*)hbA)[(size_t)b * 256 + (tid - 256)];
    __syncthreads();
    if (tid < 256){
      const float4* wr = (const float4*)w_mu + (size_t)tid * 512;
      float4 s = z4();
      #pragma unroll 4
      for (int c = 0; c < 512; ++c) fma4(s, hl4[c], wr[c]);
      st_scal(&zbuf[(size_t)b * cZ + tid], b_mu[tid] + fold4(s) * INV_S);
    }
    if (tid == 0) st_scal(&amg[b], 299.f);
    if (tid < 96) st_scal(&scg[(size_t)b * 96 + tid], (tid == 88) ? 1.f : 0.f);
  }
  GBD;
  {
    // stage z for this block's 32 batches into LDS (row stride 260 floats = 130 u64)
    float* zl = stg;
    {
      u64 tmp[8];
      const u64* zb8 = (const u64*)zbuf;
      u64* zl8 = (u64*)stg;
      #pragma unroll
      for (int q = 0; q < 8; ++q){
        const int e = q * 512 + tid;
        tmp[q] = ld_u64(zb8 + (size_t)(bbase + (e >> 7)) * 128 + (e & 127));
      }
      #pragma unroll
      for (int q = 0; q < 8; ++q){
        const int e = q * 512 + tid;
        zl8[(e >> 7) * 130 + (e & 127)] = tmp[q];
      }
    }
    __syncthreads();
    for (int e = tid; e < 768; e += 512){   // gi0z slice: 3 gates x 8 rows x 32 batches
      const int g = e >> 8, kr = (e >> 5) & 7, b = e & 31;
      const float* zr = zl + b * 260;
      const float* wrow = w_ih0 + (size_t)(g * cH + kbase + kr) * 645 + 389;
      float s = 0.f;
      #pragma unroll 4
      for (int d = 0; d < cZ; ++d) s = fmaf(zr[d], wrow[d], s);
      st_scal(&gi0z[(size_t)(g * cH + kbase + kr) * 64 + bbase + b], s);
    }
    if (tid < 256){                          // hinit slice: 8 rows x 32 batches
      const int kr = tid >> 5, b = tid & 31;
      const float4* zr4 = (const float4*)(zl + b * 260);
      const float4* wr4 = (const float4*)w_init + (size_t)(kbase + kr) * 64;
      float4 s = z4();
      #pragma unroll 4
      for (int d = 0; d < 64; ++d) fma4(s, zr4[d], wr4[d]);
      st_scal(&h0A[(size_t)(bbase + b) * cH + kbase + kr],
              tanhf(b_init[kbase + kr] + fold4(s)));
    }
  }
  GBD;

  // ================= main loop =================
  for (int j = 0; j < cT; ++j){
    const int par = j & 1;
    const float* h0p = par ? h0B : h0A;  float* h0n = par ? h0A : h0B;
    const float* h1p = par ? h1B : h1A;  float* h1n = par ? h1A : h1B;
    const float* h2p = par ? h2B : h2A;  float* h2n = par ? h2A : h2B;

    // ---- phase A: layer 0 (one-hot gather + sc GEMM + precomputed z-part + hh GEMM)
    {
      {  // stage scores (96 floats/row = 48 u64) + argmax indices
        u64 tmp[3];
        const u64* sg8 = (const u64*)scg;
        u64* sc8 = (u64*)scs;
        #pragma unroll
        for (int i = 0; i < 3; ++i){
          const int e = i * 512 + tid;           // 0..1535
          const int row = e / 48, col = e - row * 48;
          tmp[i] = ld_u64(sg8 + (size_t)(bbase + row) * 48 + col);
        }
        #pragma unroll
        for (int i = 0; i < 3; ++i){
          const int e = i * 512 + tid;
          const int row = e / 48, col = e - row * 48;
          sc8[row * 50 + col] = tmp[i];
        }
        if (tid < 32) ams[tid] = ld_scal(&amg[bbase + tid]);
      }
      __syncthreads();

      // issue first h0p stage; overlap with score GEMM + gather
      stage_issue(h0p, bbase);

      float4 R[4], Z[4], NI[4], NH[4];
      float sR[4], sZ[4], sNI[4];
      #pragma unroll
      for (int jj = 0; jj < 4; ++jj){
        R[jj]=z4(); Z[jj]=z4(); NI[jj]=z4(); NH[jj]=z4();
        sR[jj]=0.f; sZ[jj]=0.f; sNI[jj]=0.f;
      }
      {  // score GEMM: cols seg*3..+3 of 24 f4
        const float4* ws0 = (const float4*)wsc + (size_t)k * 24;
        const float4* ws1 = (const float4*)wsc + (size_t)(cH + k) * 24;
        const float4* ws2 = (const float4*)wsc + (size_t)(2*cH + k) * 24;
        const float4* sc4 = (const float4*)scs;
        #pragma unroll
        for (int c = 0; c < 3; ++c){
          const int cc = seg * 3 + c;
          const float4 w0v = ws0[cc], w1v = ws1[cc], w2v = ws2[cc];
          #pragma unroll
          for (int jj = 0; jj < 4; ++jj){
            const float4 a = sc4[(tx + 8*jj) * 25 + cc];
            fma4(R[jj], a, w0v); fma4(Z[jj], a, w1v); fma4(NI[jj], a, w2v);
          }
        }
      }
      if (seg == 0){  // one-hot gather + precomputed z-part (once per (k,b))
        #pragma unroll
        for (int jj = 0; jj < 4; ++jj){
          const int b = tx + 8*jj, gb = bbase + b;
          const int am = (int)ams[b];
          sR[jj]  = w_ih0[(size_t)k * 645 + am]
                  + ld_scal(&gi0z[(size_t)k * 64 + gb]);
          sZ[jj]  = w_ih0[(size_t)(cH + k) * 645 + am]
                  + ld_scal(&gi0z[(size_t)(cH + k) * 64 + gb]);
          sNI[jj] = w_ih0[(size_t)(2*cH + k) * 645 + am]
                  + ld_scal(&gi0z[(size_t)(2*cH + k) * 64 + gb]);
        }
      }
      const float4* wh0 = (const float4*)w_hh0 + (size_t)k * 256;
      const float4* wh1 = (const float4*)w_hh0 + (size_t)(cH + k) * 256;
      const float4* wh2 = (const float4*)w_hh0 + (size_t)(2*cH + k) * 256;
      __syncthreads();
      stage_commit(); __syncthreads();
      stage_issue(h0p, bbase + 16);
      accH(wh0, wh1, wh2, R[0], R[1], Z[0], Z[1], NH[0], NH[1]);
      __syncthreads();
      stage_commit(); __syncthreads();
      accH(wh0, wh1, wh2, R[2], R[3], Z[2], Z[3], NH[2], NH[3]);
      #pragma unroll
      for (int jj = 0; jj < 4; ++jj){
        const int b = tx + 8*jj;
        part[seg][0][ty][b] = fold4(R[jj]) + sR[jj];
        part[seg][1][ty][b] = fold4(Z[jj]) + sZ[jj];
        part[seg][2][ty][b] = fold4(NI[jj]) + sNI[jj];
        part[seg][3][ty][b] = fold4(NH[jj]);
      }
      reduce_store(b_ih0, b_hh0, h0p, h0n);
    }
    GBL;

    // ---- phases B, C: layers 1, 2 (pipelined staging)
    #pragma unroll 1
    for (int L = 0; L < 2; ++L){
      const float* inG = (L == 0) ? h0n : h1n;
      const float* pvG = (L == 0) ? (j == 0 ? h0n : h1p) : (j == 0 ? h1n : h2p);
      const float* wih = (L == 0) ? w_ih1 : w_ih2;
      const float* whh = (L == 0) ? w_hh1 : w_hh2;
      const float* bi  = (L == 0) ? b_ih1 : b_ih2;
      const float* bhv = (L == 0) ? b_hh1 : b_hh2;
      float* outG      = (L == 0) ? h1n : h2n;

      float4 R[4], Z[4], NI[4], NH[4];
      #pragma unroll
      for (int jj = 0; jj < 4; ++jj){ R[jj]=z4(); Z[jj]=z4(); NI[jj]=z4(); NH[jj]=z4(); }
      const float4* wi0 = (const float4*)wih + (size_t)k * 256;
      const float4* wi1 = (const float4*)wih + (size_t)(cH + k) * 256;
      const float4* wi2 = (const float4*)wih + (size_t)(2*cH + k) * 256;
      const float4* wh0 = (const float4*)whh + (size_t)k * 256;
      const float4* wh1 = (const float4*)whh + (size_t)(cH + k) * 256;
      const float4* wh2 = (const float4*)whh + (size_t)(2*cH + k) * 256;

      stage_issue(inG, bbase);
      stage_commit(); __syncthreads();
      stage_issue(inG, bbase + 16);
      accH(wi0, wi1, wi2, R[0], R[1], Z[0], Z[1], NI[0], NI[1]);
      __syncthreads();
      stage_commit(); __syncthreads();
      stage_issue(pvG, bbase);
      accH(wi0, wi1, wi2, R[2], R[3], Z[2], Z[3], NI[2], NI[3]);
      __syncthreads();
      stage_commit(); __syncthreads();
      stage_issue(pvG, bbase + 16);
      accH(wh0, wh1, wh2, R[0], R[1], Z[0], Z[1], NH[0], NH[1]);
      __syncthreads();
      stage_commit(); __syncthreads();
      accH(wh0, wh1, wh2, R[2], R[3], Z[2], Z[3], NH[2], NH[3]);
      #pragma unroll
      for (int jj = 0; jj < 4; ++jj){
        const int b = tx + 8*jj;
        part[seg][0][ty][b] = fold4(R[jj]);
        part[seg][1][ty][b] = fold4(Z[jj]);
        part[seg][2][ty][b] = fold4(NI[jj]);
        part[seg][3][ty][b] = fold4(NH[jj]);
      }
      reduce_store(bi, bhv, pvG, outG);
      GBL;
    }

    // ---- phase FOLD: 32 blocks per bh domain (kq<32) — logits + log_softmax +
    //      argmax + next-step am/sc for batch b = bbase + kq
    if (kq < 32){
      const int b = bbase + kq;
      ((u64*)hb2)[tid] = ld_u64((const u64*)h2n + (size_t)b * 512 + tid);
      __syncthreads();
      for (int p = tid; p < cPF; p += 512){
        const float4* wr = (const float4*)w_out + (size_t)p * 256;
        const float4* hv = (const float4*)hb2;
        float4 s = z4();
        #pragma unroll 4
        for (int c = 0; c < 256; ++c) fma4(s, hv[c], wr[c]);
        lg[p] = b_out[p] + fold4(s);
      }
      __syncthreads();
      const int w = tid >> 6, l = tid & 63;
      if (w < 3){
        float m = -INFINITY;
        for (int p = w*100 + l; p < w*100 + 100; p += 64) m = fmaxf(m, lg[p]);
        #pragma unroll
        for (int off = 32; off > 0; off >>= 1) m = fmaxf(m, __shfl_xor(m, off));
        float s = 0.f;
        for (int p = w*100 + l; p < w*100 + 100; p += 64) s += expf(lg[p] - m);
        #pragma unroll
        for (int off = 32; off > 0; off >>= 1) s += __shfl_xor(s, off);
        if (l == 0){ gmax[w] = m; glse[w] = logf(s); }
      }
      __syncthreads();
      float best = -INFINITY; int bidx = 0x7fffffff;
      for (int p = tid; p < cPF; p += 512){
        const int g3 = (p >= 200) ? 2 : ((p >= 100) ? 1 : 0);
        const float o = lg[p] - gmax[g3] - glse[g3];
        dout[((size_t)b * cT + j) * cPF + p] = o;
        if (o > best || (o == best && p < bidx)){ best = o; bidx = p; }
      }
      #pragma unroll
      for (int off = 32; off > 0; off >>= 1){
        const float ob = __shfl_xor(best, off);
        const int   oi = __shfl_xor(bidx, off);
        if (ob > best || (ob == best && oi < bidx)){ best = ob; bidx = oi; }
      }
      if (l == 0){ wbest[w] = best; wbidx[w] = bidx; }
      __syncthreads();
      if (tid == 0){
        float bb = wbest[0]; int bi = wbidx[0];
        #pragma unroll
        for (int q = 1; q < 8; ++q)
          if (wbest[q] > bb || (wbest[q] == bb && wbidx[q] < bi)){ bb = wbest[q]; bi = wbidx[q]; }
        st_scal(&amg[b], (float)bi);
      }
      if (tid < 96)
        st_scal(&scg[(size_t)b * 96 + tid],
                (tid < cSC) ? x[((size_t)j * cB + b) * cR + tid] : 0.f);
    }
    GBL;
  }
  #undef GBD
  #undef GBL
}

} // namespace

// ---------------------------------------------------------------- host
extern "C" void kernel_launch(void* const* d_in, const int* in_sizes, int n_in,
                              void* d_out, int out_size, void* d_ws, size_t ws_size,
                              hipStream_t stream)
{
  const float* x     = (const float*)d_in[0];
  const float* wih_f = (const float*)d_in[2];
  const float* whh_f = (const float*)d_in[3];
  const float* bih_f = (const float*)d_in[4];
  const float* bhh_f = (const float*)d_in[5];
  const float* wih_b = (const float*)d_in[6];
  const float* whh_b = (const float*)d_in[7];
  const float* bih_b = (const float*)d_in[8];
  const float* bhh_b = (const float*)d_in[9];
  const float* w_mu  = (const float*)d_in[10];
  const float* b_mu  = (const float*)d_in[11];
  const float* w_init= (const float*)d_in[14];
  const float* b_init= (const float*)d_in[15];
  const float* w_ih0 = (const float*)d_in[16];
  const float* w_hh0 = (const float*)d_in[17];
  const float* b_ih0 = (const float*)d_in[18];
  const float* b_hh0 = (const float*)d_in[19];
  const float* w_ih1 = (const float*)d_in[20];
  const float* w_hh1 = (const float*)d_in[21];
  const float* b_ih1 = (const float*)d_in[22];
  const float* b_hh1 = (const float*)d_in[23];
  const float* w_ih2 = (const float*)d_in[24];
  const float* w_hh2 = (const float*)d_in[25];
  const float* b_ih2 = (const float*)d_in[26];
  const float* b_hh2 = (const float*)d_in[27];
  const float* w_out = (const float*)d_in[28];
  const float* b_out = (const float*)d_in[29];
  float* dout = (float*)d_out;

  float* ws = (float*)d_ws;
  float* wihfP = ws; ws += (size_t)3 * cH * WSTR;     // 4.9 MB
  float* wihbP = ws; ws += (size_t)3 * cH * WSTR;     // 4.9 MB
  float* wsc   = ws; ws += (size_t)3 * cH * 96;       // 1.2 MB
  float* gi0z  = ws; ws += (size_t)3 * cH * 64;       // 0.8 MB
  float* hfA = ws; ws += cB * cH;  float* hfB = ws; ws += cB * cH;
  float* hbA = ws; ws += cB * cH;  float* hbB = ws; ws += cB * cH;
  float* h0A = ws; ws += cB * cH;  float* h0B = ws; ws += cB * cH;
  float* h1A = ws; ws += cB * cH;  float* h1B = ws; ws += cB * cH;
  float* h2A = ws; ws += cB * cH;  float* h2B = ws; ws += cB * cH;
  float* zbuf = ws; ws += cB * cZ;
  float* scg  = ws; ws += cB * 96;
  float* amg  = ws; ws += cB;
  ws = (float*)(((uintptr_t)ws + 255) & ~(uintptr_t)255);
  unsigned* barE = (unsigned*)ws;  ws += 2048;  // 4 domains x 512
  unsigned* barD = (unsigned*)ws;  ws += 2048;  // prologue 256-dom + 2 loop domains

  init_kernel<<<256, 256, 0, stream>>>(hfA, hbA, dout + (size_t)cB * cT * cPF, barE, barD);
  pad_wih_kernel<<<512, 256, 0, stream>>>(wih_f, wihfP);
  pad_wih_kernel<<<512, 256, 0, stream>>>(wih_b, wihbP);
  pad_wsc_kernel<<<512, 256, 0, stream>>>(w_ih0, wsc);

  enc_persist<<<256, 512, 0, stream>>>(
      x,
      wihfP, whh_f, bih_f, bhh_f,
      wihbP, whh_b, bih_b, bhh_b,
      hfA, hfB, hbA, hbB, barE);

  dec_persist<<<256, 512, 0, stream>>>(
      x, hfA, hbA,
      w_mu, b_mu, w_init, b_init,
      w_ih0, wsc, w_hh0, b_ih0, b_hh0,
      w_ih1, w_hh1, b_ih1, b_hh1,
      w_ih2, w_hh2, b_ih2, b_hh2,
      w_out, b_out,
      h0A, h0B, h1A, h1B, h2A, h2B,
      gi0z, zbuf, amg, scg, dout, barD);
}

// Round 15
// 54797.845 us; speedup vs baseline: 5.0768x; 1.0299x over previous
//
#include <hip/hip_runtime.h>
#include <math.h>

namespace {

typedef unsigned long long u64;

constexpr int cH  = 1024;
constexpr int cZ  = 256;
constexpr int cB  = 64;
constexpr int cT  = 256;
constexpr int cR  = 389;
constexpr int cSC = 89;
constexpr int cPF = 300;
constexpr int WSTR = 400;               // padded encoder w_ih stride (floats) = 100 f4
constexpr float INV_S = 0.9999950000374997f;  // 1/sqrt(1+1e-5)

__device__ __forceinline__ void fma4(float4& a, const float4 x, const float4 w){
  a.x = fmaf(x.x, w.x, a.x);
  a.y = fmaf(x.y, w.y, a.y);
  a.z = fmaf(x.z, w.z, a.z);
  a.w = fmaf(x.w, w.w, a.w);
}
__device__ __forceinline__ float fold4(const float4 a){ return (a.x + a.y) + (a.z + a.w); }
__device__ __forceinline__ float4 z4(){ return make_float4(0.f, 0.f, 0.f, 0.f); }
__device__ __forceinline__ float sigm(float x){ return 1.f / (1.f + expf(-x)); }

// ---- guaranteed-coherent primitives (compiler-tracked; no inline-asm data movement) ----
__device__ __forceinline__ void cfence(){ asm volatile("" ::: "memory"); }
__device__ __forceinline__ u64 ld_u64(const u64* p){
  return __hip_atomic_load(p, __ATOMIC_RELAXED, __HIP_MEMORY_SCOPE_AGENT);
}
__device__ __forceinline__ float ld_scal(const float* p){
  return __hip_atomic_load(p, __ATOMIC_RELAXED, __HIP_MEMORY_SCOPE_AGENT);
}
__device__ __forceinline__ void st_scal(float* p, float v){
  __hip_atomic_store(p, v, __ATOMIC_RELAXED, __HIP_MEMORY_SCOPE_AGENT);
}

// ---- two-level group barrier; RELEASE arrival orders prior agent stores ----
__device__ __forceinline__ void gbarN(unsigned* base, int sub, unsigned subCnt,
                                      int nsub, unsigned rootCnt){
  __syncthreads();
  if (threadIdx.x == 0){
    cfence();
    unsigned* root = base + nsub * 16;
    unsigned* gen  = base + nsub * 16 + 16;
    const unsigned g = __hip_atomic_load(gen, __ATOMIC_RELAXED, __HIP_MEMORY_SCOPE_AGENT);
    const unsigned a = __hip_atomic_fetch_add(base + sub * 16, 1u,
                         __ATOMIC_RELEASE, __HIP_MEMORY_SCOPE_AGENT);
    bool flip = false;
    if (a == subCnt - 1u){
      const unsigned r = __hip_atomic_fetch_add(root, 1u,
                           __ATOMIC_RELEASE, __HIP_MEMORY_SCOPE_AGENT);
      if (r == rootCnt - 1u){
        for (int t = 0; t < nsub; ++t)
          __hip_atomic_store(base + t * 16, 0u, __ATOMIC_RELAXED, __HIP_MEMORY_SCOPE_AGENT);
        __hip_atomic_store(root, 0u, __ATOMIC_RELAXED, __HIP_MEMORY_SCOPE_AGENT);
        __hip_atomic_store(gen, g + 1u, __ATOMIC_RELEASE, __HIP_MEMORY_SCOPE_AGENT);
        flip = true;
      }
    }
    if (!flip){
      while (__hip_atomic_load(gen, __ATOMIC_RELAXED, __HIP_MEMORY_SCOPE_AGENT) == g)
        __builtin_amdgcn_s_sleep(1);
    }
    cfence();
  }
  __syncthreads();
}

// ---------------------------------------------------------------- prep kernels
__global__ __launch_bounds__(256) void init_kernel(float* hf0, float* hb0, float* dout_tail,
                                                   unsigned* barE, unsigned* barD){
  const int idx = blockIdx.x * 256 + threadIdx.x;
  const int stride = gridDim.x * 256;
  for (int i = idx; i < cB * cH; i += stride){ hf0[i] = 0.f; hb0[i] = 0.f; }
  for (int i = idx; i < 2 * cB * cZ; i += stride) dout_tail[i] = 0.f;
  for (int i = idx; i < 2048; i += stride){ barE[i] = 0u; barD[i] = 0u; }
}

__global__ __launch_bounds__(256) void pad_wih_kernel(const float* __restrict__ w,
                                                      float* __restrict__ wp){
  const int idx = blockIdx.x * 256 + threadIdx.x;
  const int stride = gridDim.x * 256;
  const int n = 3 * cH * WSTR;
  for (int i = idx; i < n; i += stride){
    const int r = i / WSTR, c = i - r * WSTR;
    wp[i] = (c < cR) ? w[(size_t)r * cR + c] : 0.f;
  }
}

__global__ __launch_bounds__(256) void pad_wsc_kernel(const float* __restrict__ w_ih0,
                                                      float* __restrict__ wsc){
  const int idx = blockIdx.x * 256 + threadIdx.x;
  const int stride = gridDim.x * 256;
  const int n = 3 * cH * 96;
  for (int i = idx; i < n; i += stride){
    const int r = i / 96, c = i - r * 96;
    wsc[i] = (c < cSC) ? w_ih0[(size_t)r * 645 + 300 + c] : 0.f;
  }
}

// ---------------------------------------------------------------- encoder (persistent)
// 256 blocks: xcd=bid&7, slot=bid>>3; dir=slot>>4, sub16=slot&15;
// kblk = xcd*8 + (sub16>>1) (16 k-rows), bhalf = sub16&1 (32 batches).
__global__ __launch_bounds__(512, 2) void enc_persist(
    const float* __restrict__ x,
    const float* __restrict__ wihPf, const float* __restrict__ whh_f,
    const float* __restrict__ bih_f, const float* __restrict__ bhh_f,
    const float* __restrict__ wihPb, const float* __restrict__ whh_b,
    const float* __restrict__ bih_b, const float* __restrict__ bhh_b,
    float* __restrict__ hfA, float* __restrict__ hfB,
    float* __restrict__ hbA, float* __restrict__ hbB,
    unsigned* __restrict__ barE)
{
  const int bid   = blockIdx.x;
  const int xcd   = bid & 7;
  const int slot  = bid >> 3;
  const int dir   = slot >> 4;
  const int sub16 = slot & 15;
  const int kblk  = xcd * 8 + (sub16 >> 1);
  const int bhalf = sub16 & 1;
  unsigned* bar   = barE + (dir * 2 + bhalf) * 512;

  const float* wih = dir ? wihPb : wihPf;
  const float* whh = dir ? whh_b : whh_f;
  const float* bih = dir ? bih_b : bih_f;
  const float* bhh = dir ? bhh_b : bhh_f;
  float* bufA = dir ? hbA : hfA;
  float* bufB = dir ? hbB : hfB;

  const int tid   = threadIdx.x;
  const int seg8  = tid >> 6;
  const int dseg  = seg8 & 3;
  const int khalf = seg8 >> 2;
  const int lane  = tid & 63;
  const int tx    = lane & 7;
  const int ty    = lane >> 3;
  const int k0    = kblk * 16;
  const int bbase = bhalf * 32;
  const int kloc  = khalf * 8 + ty;      // 0..15
  const int k     = k0 + kloc;

  __shared__ float part[4][4][16][33];            // 33.8 KB
  __shared__ alignas(16) float sh[32 * 516];      // 66 KB: 32 rows x 129 f4

  const float4* w0i = (const float4*)wih + (size_t)k * 100;
  const float4* w1i = (const float4*)wih + (size_t)(cH + k) * 100;
  const float4* w2i = (const float4*)wih + (size_t)(2*cH + k) * 100;
  const float4* w0h = (const float4*)whh + (size_t)k * 256;
  const float4* w1h = (const float4*)whh + (size_t)(cH + k) * 256;
  const float4* w2h = (const float4*)whh + (size_t)(2*cH + k) * 256;
  float4* sh4 = (float4*)sh;

  u64 S[16];
  auto stage_issue = [&](const float* hin, int p){
    const u64* s8 = (const u64*)hin;
    #pragma unroll
    for (int i = 0; i < 16; ++i){
      const int e = i * 512 + tid;
      S[i] = ld_u64(s8 + (size_t)(bbase + (e >> 8)) * 512 + p * 256 + (e & 255));
    }
    cfence();
  };
  auto stage_commit = [&](){
    u64* d8 = (u64*)sh;
    #pragma unroll
    for (int i = 0; i < 16; ++i){
      const int e = i * 512 + tid;
      d8[(e >> 8) * 258 + (e & 255)] = S[i];
    }
  };

  for (int t = 0; t < cT; ++t){
    const float* hin = (t & 1) ? bufB : bufA;
    float*      hout = (t & 1) ? bufA : bufB;
    const int tt = dir ? (cT - 1 - t) : t;

    float4 R[4], Z[4], NI[4], NH[4];
    #pragma unroll
    for (int jj = 0; jj < 4; ++jj){ R[jj]=z4(); Z[jj]=z4(); NI[jj]=z4(); NH[jj]=z4(); }

    // issue first h-half stage; overlap with x GEMM
    stage_issue(hin, 0);

    // ---- phase 1: x @ w_ih^T (padded f4 weights, clamped scalar x reads)
    {
      const float* xb[4];
      #pragma unroll
      for (int jj = 0; jj < 4; ++jj)
        xb[jj] = x + ((size_t)tt * cB + bbase + tx + 8*jj) * cR;
      const int c0 = dseg * 25;
      const int cEnd = c0 + 25;
      const int cSafe = (cEnd < 97) ? cEnd : 97;
      for (int c = c0; c < cSafe; ++c){
        const float4 w0v = w0i[c], w1v = w1i[c], w2v = w2i[c];
        const int d = 4 * c;
        #pragma unroll
        for (int jj = 0; jj < 4; ++jj){
          const float* xr = xb[jj];
          const float4 a = make_float4(xr[d], xr[d+1], xr[d+2], xr[d+3]);
          fma4(R[jj], a, w0v); fma4(Z[jj], a, w1v); fma4(NI[jj], a, w2v);
        }
      }
      for (int c = cSafe; c < cEnd; ++c){
        const float4 w0v = w0i[c], w1v = w1i[c], w2v = w2i[c];
        const int d = 4 * c;
        #pragma unroll
        for (int jj = 0; jj < 4; ++jj){
          const float* xr = xb[jj];
          const float4 a = make_float4(
              (d   < cR) ? xr[d]   : 0.f, (d+1 < cR) ? xr[d+1] : 0.f,
              (d+2 < cR) ? xr[d+2] : 0.f, (d+3 < cR) ? xr[d+3] : 0.f);
          fma4(R[jj], a, w0v); fma4(Z[jj], a, w1v); fma4(NI[jj], a, w2v);
        }
      }
    }

    // ---- phase 2: h @ w_hh^T, two halves, pipelined
    stage_commit();
    __syncthreads();
    stage_issue(hin, 1);
    {
      #pragma unroll 4
      for (int c = 0; c < 32; ++c){
        const int cc = dseg * 32 + c;
        const float4 w0v = w0h[cc], w1v = w1h[cc], w2v = w2h[cc];
        #pragma unroll
        for (int jj = 0; jj < 4; ++jj){
          const float4 a = sh4[(tx + 8*jj)*129 + cc];
          fma4(R[jj], a, w0v); fma4(Z[jj], a, w1v); fma4(NH[jj], a, w2v);
        }
      }
    }
    __syncthreads();
    stage_commit();
    __syncthreads();
    {
      const float4* wp0 = w0h + 128;
      const float4* wp1 = w1h + 128;
      const float4* wp2 = w2h + 128;
      #pragma unroll 4
      for (int c = 0; c < 32; ++c){
        const int cc = dseg * 32 + c;
        const float4 w0v = wp0[cc], w1v = wp1[cc], w2v = wp2[cc];
        #pragma unroll
        for (int jj = 0; jj < 4; ++jj){
          const float4 a = sh4[(tx + 8*jj)*129 + cc];
          fma4(R[jj], a, w0v); fma4(Z[jj], a, w1v); fma4(NH[jj], a, w2v);
        }
      }
    }
    __syncthreads();

    #pragma unroll
    for (int jj = 0; jj < 4; ++jj){
      const int b = tx + 8*jj;
      part[dseg][0][kloc][b] = fold4(R[jj]);
      part[dseg][1][kloc][b] = fold4(Z[jj]);
      part[dseg][2][kloc][b] = fold4(NI[jj]);
      part[dseg][3][kloc][b] = fold4(NH[jj]);
    }
    __syncthreads();
    {
      const int row = tid >> 5, bb = tid & 31;   // 16 x 32 = 512 outputs
      float rs=0.f, zs=0.f, nis=0.f, nhs=0.f;
      #pragma unroll
      for (int s = 0; s < 4; ++s){
        rs += part[s][0][row][bb]; zs += part[s][1][row][bb];
        nis += part[s][2][row][bb]; nhs += part[s][3][row][bb];
      }
      const int kk = k0 + row, gb = bbase + bb;
      const float r  = sigm(rs + bih[kk] + bhh[kk]);
      const float zg = sigm(zs + bih[cH + kk] + bhh[cH + kk]);
      const float nn = tanhf(nis + bih[2*cH + kk] + r * (nhs + bhh[2*cH + kk]));
      const float hp = ld_scal(&hin[(size_t)gb * cH + kk]);
      st_scal(&hout[(size_t)gb * cH + kk], (1.f - zg) * nn + zg * hp);
    }
    gbarN(bar, kblk >> 3, 8u, 8, 8u);
  }
}

// ---------------------------------------------------------------- decoder (persistent)
// 256 blocks, XCD-swizzled: xcd=bid&7, slot=bid>>3; kq = xcd*16 + (slot>>1) (8 k-rows),
// bh = slot&1 (32 batches).  Prologue barrier: 256-block domain; loop: per-bh 128.
__global__ __launch_bounds__(512, 2) void dec_persist(
    const float* __restrict__ x,
    const float* __restrict__ hfA, const float* __restrict__ hbA,
    const float* __restrict__ w_mu, const float* __restrict__ b_mu,
    const float* __restrict__ w_init, const float* __restrict__ b_init,
    const float* __restrict__ w_ih0,
    const float* __restrict__ wsc,   const float* __restrict__ w_hh0,
    const float* __restrict__ b_ih0, const float* __restrict__ b_hh0,
    const float* __restrict__ w_ih1, const float* __restrict__ w_hh1,
    const float* __restrict__ b_ih1, const float* __restrict__ b_hh1,
    const float* __restrict__ w_ih2, const float* __restrict__ w_hh2,
    const float* __restrict__ b_ih2, const float* __restrict__ b_hh2,
    const float* __restrict__ w_out, const float* __restrict__ b_out,
    float* __restrict__ h0A, float* __restrict__ h0B,
    float* __restrict__ h1A, float* __restrict__ h1B,
    float* __restrict__ h2A, float* __restrict__ h2B,
    float* __restrict__ gi0z, float* __restrict__ zbuf,
    float* __restrict__ amg,
    float* __restrict__ dout,
    unsigned* __restrict__ barD)
{
  const int bid  = blockIdx.x;
  const int xcd  = bid & 7;
  const int slot = bid >> 3;
  const int kq   = xcd * 16 + (slot >> 1);
  const int bh   = slot & 1;
  const int kbase = kq * 8;
  const int bbase = bh * 32;
  const int tid = threadIdx.x;

  const int seg  = tid >> 6;
  const int lane = tid & 63;
  const int tx   = lane & 7;
  const int ty   = lane >> 3;
  const int k    = kbase + ty;

  __shared__ float part[8][4][8][33];              // 33.8 KB
  __shared__ alignas(16) float stg[16 * 1028];     // 65.8 KB (16 rows x 257 f4)
  __shared__ alignas(16) float scs[32 * 100];      // 12.8 KB
  __shared__ float ams[32];
  __shared__ alignas(16) float hb2[cH];            // 4 KB (fold)
  __shared__ float lg[cPF];
  __shared__ float gmax[3], glse[3], wbest[8];
  __shared__ int   wbidx[8];

  float4* stg4 = (float4*)stg;

  #define GBD  gbarN(barD, bid >> 4, 16u, 16, 16u)
  unsigned* barL = barD + 512 + bh * 512;
  #define GBL  gbarN(barL, kq >> 4, 16u, 8, 8u)

  u64 S[16];
  auto stage_issue = [&](const float* src, int gb0){
    const u64* s8 = (const u64*)src;
    #pragma unroll
    for (int i = 0; i < 16; ++i){
      const int e = i * 512 + tid;
      S[i] = ld_u64(s8 + (size_t)(gb0 + (e >> 9)) * 512 + (e & 511));
    }
    cfence();
  };
  auto stage_commit = [&](){
    u64* d8 = (u64*)stg;
    #pragma unroll
    for (int i = 0; i < 16; ++i){
      const int e = i * 512 + tid;
      d8[(e >> 9) * 514 + (e & 511)] = S[i];
    }
  };

  // accumulate stage rows tx and tx+8 over cols seg*32..+32
  auto accH = [&](const float4* w0, const float4* w1, const float4* w2,
                  float4& A0, float4& A1, float4& B0, float4& B1,
                  float4& C0, float4& C1){
    #pragma unroll 4
    for (int c = 0; c < 32; ++c){
      const int cc = seg * 32 + c;
      const float4 w0v = w0[cc], w1v = w1[cc], w2v = w2[cc];
      const float4 aA = stg4[tx * 257 + cc];
      const float4 aB = stg4[(tx + 8) * 257 + cc];
      fma4(A0, aA, w0v); fma4(B0, aA, w1v); fma4(C0, aA, w2v);
      fma4(A1, aB, w0v); fma4(B1, aB, w1v); fma4(C1, aB, w2v);
    }
  };

  auto reduce_store = [&](const float* bi, const float* bhv,
                          const float* hprev, float* hout){
    __syncthreads();
    if (tid < 256){
      const int row = tid >> 5, b = tid & 31;
      float rs=0.f, zs=0.f, nis=0.f, nhs=0.f;
      #pragma unroll
      for (int s = 0; s < 8; ++s){
        rs += part[s][0][row][b]; zs += part[s][1][row][b];
        nis += part[s][2][row][b]; nhs += part[s][3][row][b];
      }
      const int kk = kbase + row, gb = bbase + b;
      const float r  = sigm(rs + bi[kk] + bhv[kk]);
      const float zg = sigm(zs + bi[cH + kk] + bhv[cH + kk]);
      const float nn = tanhf(nis + bi[2*cH + kk] + r * (nhs + bhv[2*cH + kk]));
      const float hp = ld_scal(&hprev[(size_t)gb * cH + kk]);
      st_scal(&hout[(size_t)gb * cH + kk], (1.f - zg) * nn + zg * hp);
    }
  };

  // ================= prologue =================
  if (bid < cB){
    const int b = bid;
    float4* hl4 = (float4*)stg;
    hl4[tid] = (tid < 256) ? ((const float4*)hfA)[(size_t)b * 256 + tid]
                           : ((const float4*)hbA)[(size_t)b * 256 + (tid - 256)];
    __syncthreads();
    if (tid < 256){
      const float4* wr = (const float4*)w_mu + (size_t)tid * 512;
      float4 s = z4();
      #pragma unroll 4
      for (int c = 0; c < 512; ++c) fma4(s, hl4[c], wr[c]);
      st_scal(&zbuf[(size_t)b * cZ + tid], b_mu[tid] + fold4(s) * INV_S);
    }
    if (tid == 0) st_scal(&amg[b], 299.f);
  }
  GBD;
  {
    // stage z for this block's 32 batches into LDS (coherent u64 reads)
    float* zl = stg;
    {
      u64 tmp[8];
      const u64* zb8 = (const u64*)zbuf;
      u64* zl8 = (u64*)stg;
      #pragma unroll
      for (int q = 0; q < 8; ++q){
        const int e = q * 512 + tid;
        tmp[q] = ld_u64(zb8 + (size_t)(bbase + (e >> 7)) * 128 + (e & 127));
      }
      #pragma unroll
      for (int q = 0; q < 8; ++q){
        const int e = q * 512 + tid;
        zl8[(e >> 7) * 130 + (e & 127)] = tmp[q];
      }
    }
    __syncthreads();
    for (int e = tid; e < 768; e += 512){   // gi0z slice: 3 gates x 8 rows x 32 batches
      const int g = e >> 8, kr = (e >> 5) & 7, b = e & 31;
      const float* zr = zl + b * 260;
      const float* wrow = w_ih0 + (size_t)(g * cH + kbase + kr) * 645 + 389;
      float s = 0.f;
      #pragma unroll 4
      for (int d = 0; d < cZ; ++d) s = fmaf(zr[d], wrow[d], s);
      st_scal(&gi0z[(size_t)(g * cH + kbase + kr) * 64 + bbase + b], s);
    }
    if (tid < 256){                          // hinit slice: 8 rows x 32 batches
      const int kr = tid >> 5, b = tid & 31;
      const float4* zr4 = (const float4*)(zl + b * 260);
      const float4* wr4 = (const float4*)w_init + (size_t)(kbase + kr) * 64;
      float4 s = z4();
      #pragma unroll 4
      for (int d = 0; d < 64; ++d) fma4(s, zr4[d], wr4[d]);
      st_scal(&h0A[(size_t)(bbase + b) * cH + kbase + kr],
              tanhf(b_init[kbase + kr] + fold4(s)));
    }
  }
  GBD;

  // ================= main loop =================
  for (int j = 0; j < cT; ++j){
    const int par = j & 1;
    const float* h0p = par ? h0B : h0A;  float* h0n = par ? h0A : h0B;
    const float* h1p = par ? h1B : h1A;  float* h1n = par ? h1A : h1B;
    const float* h2p = par ? h2B : h2A;  float* h2n = par ? h2A : h2B;

    // ---- phase A: layer 0 (one-hot gather + sc GEMM + precomputed z-part + hh GEMM)
    {
      // build scores in LDS directly from read-only x (no coherent round-trip)
      if (j == 0){
        for (int e = tid; e < 32 * 96; e += 512){
          const int b = e / 96, c = e - b * 96;
          scs[b * 100 + c] = (c == cSC - 1) ? 1.f : 0.f;
        }
      } else {
        for (int e = tid; e < 32 * 96; e += 512){
          const int b = e / 96, c = e - b * 96;
          scs[b * 100 + c] =
              (c < cSC) ? x[((size_t)(j - 1) * cB + bbase + b) * cR + c] : 0.f;
        }
      }
      if (tid < 32) ams[tid] = ld_scal(&amg[bbase + tid]);
      __syncthreads();

      // issue first h0p stage; overlap with score GEMM + gather
      stage_issue(h0p, bbase);

      float4 R[4], Z[4], NI[4], NH[4];
      float sR[4], sZ[4], sNI[4];
      #pragma unroll
      for (int jj = 0; jj < 4; ++jj){
        R[jj]=z4(); Z[jj]=z4(); NI[jj]=z4(); NH[jj]=z4();
        sR[jj]=0.f; sZ[jj]=0.f; sNI[jj]=0.f;
      }
      {  // score GEMM: cols seg*3..+3 of 24 f4
        const float4* ws0 = (const float4*)wsc + (size_t)k * 24;
        const float4* ws1 = (const float4*)wsc + (size_t)(cH + k) * 24;
        const float4* ws2 = (const float4*)wsc + (size_t)(2*cH + k) * 24;
        const float4* sc4 = (const float4*)scs;
        #pragma unroll
        for (int c = 0; c < 3; ++c){
          const int cc = seg * 3 + c;
          const float4 w0v = ws0[cc], w1v = ws1[cc], w2v = ws2[cc];
          #pragma unroll
          for (int jj = 0; jj < 4; ++jj){
            const float4 a = sc4[(tx + 8*jj) * 25 + cc];
            fma4(R[jj], a, w0v); fma4(Z[jj], a, w1v); fma4(NI[jj], a, w2v);
          }
        }
      }
      if (seg == 0){  // one-hot gather + precomputed z-part (gi0z constant -> plain loads)
        #pragma unroll
        for (int jj = 0; jj < 4; ++jj){
          const int b = tx + 8*jj, gb = bbase + b;
          const int am = (int)ams[b];
          sR[jj]  = w_ih0[(size_t)k * 645 + am]          + gi0z[(size_t)k * 64 + gb];
          sZ[jj]  = w_ih0[(size_t)(cH + k) * 645 + am]   + gi0z[(size_t)(cH + k) * 64 + gb];
          sNI[jj] = w_ih0[(size_t)(2*cH + k) * 645 + am] + gi0z[(size_t)(2*cH + k) * 64 + gb];
        }
      }
      const float4* wh0 = (const float4*)w_hh0 + (size_t)k * 256;
      const float4* wh1 = (const float4*)w_hh0 + (size_t)(cH + k) * 256;
      const float4* wh2 = (const float4*)w_hh0 + (size_t)(2*cH + k) * 256;
      __syncthreads();
      stage_commit(); __syncthreads();
      stage_issue(h0p, bbase + 16);
      accH(wh0, wh1, wh2, R[0], R[1], Z[0], Z[1], NH[0], NH[1]);
      __syncthreads();
      stage_commit(); __syncthreads();
      accH(wh0, wh1, wh2, R[2], R[3], Z[2], Z[3], NH[2], NH[3]);
      #pragma unroll
      for (int jj = 0; jj < 4; ++jj){
        const int b = tx + 8*jj;
        part[seg][0][ty][b] = fold4(R[jj]) + sR[jj];
        part[seg][1][ty][b] = fold4(Z[jj]) + sZ[jj];
        part[seg][2][ty][b] = fold4(NI[jj]) + sNI[jj];
        part[seg][3][ty][b] = fold4(NH[jj]);
      }
      reduce_store(b_ih0, b_hh0, h0p, h0n);
    }
    GBL;

    // ---- phases B, C: layers 1, 2 (pipelined staging)
    #pragma unroll 1
    for (int L = 0; L < 2; ++L){
      const float* inG = (L == 0) ? h0n : h1n;
      const float* pvG = (L == 0) ? (j == 0 ? h0n : h1p) : (j == 0 ? h1n : h2p);
      const float* wih = (L == 0) ? w_ih1 : w_ih2;
      const float* whh = (L == 0) ? w_hh1 : w_hh2;
      const float* bi  = (L == 0) ? b_ih1 : b_ih2;
      const float* bhv = (L == 0) ? b_hh1 : b_hh2;
      float* outG      = (L == 0) ? h1n : h2n;

      float4 R[4], Z[4], NI[4], NH[4];
      #pragma unroll
      for (int jj = 0; jj < 4; ++jj){ R[jj]=z4(); Z[jj]=z4(); NI[jj]=z4(); NH[jj]=z4(); }
      const float4* wi0 = (const float4*)wih + (size_t)k * 256;
      const float4* wi1 = (const float4*)wih + (size_t)(cH + k) * 256;
      const float4* wi2 = (const float4*)wih + (size_t)(2*cH + k) * 256;
      const float4* wh0 = (const float4*)whh + (size_t)k * 256;
      const float4* wh1 = (const float4*)whh + (size_t)(cH + k) * 256;
      const float4* wh2 = (const float4*)whh + (size_t)(2*cH + k) * 256;

      stage_issue(inG, bbase);
      stage_commit(); __syncthreads();
      stage_issue(inG, bbase + 16);
      accH(wi0, wi1, wi2, R[0], R[1], Z[0], Z[1], NI[0], NI[1]);
      __syncthreads();
      stage_commit(); __syncthreads();
      stage_issue(pvG, bbase);
      accH(wi0, wi1, wi2, R[2], R[3], Z[2], Z[3], NI[2], NI[3]);
      __syncthreads();
      stage_commit(); __syncthreads();
      stage_issue(pvG, bbase + 16);
      accH(wh0, wh1, wh2, R[0], R[1], Z[0], Z[1], NH[0], NH[1]);
      __syncthreads();
      stage_commit(); __syncthreads();
      accH(wh0, wh1, wh2, R[2], R[3], Z[2], Z[3], NH[2], NH[3]);
      #pragma unroll
      for (int jj = 0; jj < 4; ++jj){
        const int b = tx + 8*jj;
        part[seg][0][ty][b] = fold4(R[jj]);
        part[seg][1][ty][b] = fold4(Z[jj]);
        part[seg][2][ty][b] = fold4(NI[jj]);
        part[seg][3][ty][b] = fold4(NH[jj]);
      }
      reduce_store(bi, bhv, pvG, outG);
      GBL;
    }

    // ---- phase FOLD: 32 blocks per bh domain (kq<32) — logits + log_softmax +
    //      argmax + next-step am for batch b = bbase + kq
    if (kq < 32){
      const int b = bbase + kq;
      ((u64*)hb2)[tid] = ld_u64((const u64*)h2n + (size_t)b * 512 + tid);
      __syncthreads();
      for (int p = tid; p < cPF; p += 512){
        const float4* wr = (const float4*)w_out + (size_t)p * 256;
        const float4* hv = (const float4*)hb2;
        float4 s = z4();
        #pragma unroll 4
        for (int c = 0; c < 256; ++c) fma4(s, hv[c], wr[c]);
        lg[p] = b_out[p] + fold4(s);
      }
      __syncthreads();
      const int w = tid >> 6, l = tid & 63;
      if (w < 3){
        float m = -INFINITY;
        for (int p = w*100 + l; p < w*100 + 100; p += 64) m = fmaxf(m, lg[p]);
        #pragma unroll
        for (int off = 32; off > 0; off >>= 1) m = fmaxf(m, __shfl_xor(m, off));
        float s = 0.f;
        for (int p = w*100 + l; p < w*100 + 100; p += 64) s += expf(lg[p] - m);
        #pragma unroll
        for (int off = 32; off > 0; off >>= 1) s += __shfl_xor(s, off);
        if (l == 0){ gmax[w] = m; glse[w] = logf(s); }
      }
      __syncthreads();
      float best = -INFINITY; int bidx = 0x7fffffff;
      for (int p = tid; p < cPF; p += 512){
        const int g3 = (p >= 200) ? 2 : ((p >= 100) ? 1 : 0);
        const float o = lg[p] - gmax[g3] - glse[g3];
        dout[((size_t)b * cT + j) * cPF + p] = o;
        if (o > best || (o == best && p < bidx)){ best = o; bidx = p; }
      }
      #pragma unroll
      for (int off = 32; off > 0; off >>= 1){
        const float ob = __shfl_xor(best, off);
        const int   oi = __shfl_xor(bidx, off);
        if (ob > best || (ob == best && oi < bidx)){ best = ob; bidx = oi; }
      }
      if (l == 0){ wbest[w] = best; wbidx[w] = bidx; }
      __syncthreads();
      if (tid == 0){
        float bb = wbest[0]; int bi = wbidx[0];
        #pragma unroll
        for (int q = 1; q < 8; ++q)
          if (wbest[q] > bb || (wbest[q] == bb && wbidx[q] < bi)){ bb = wbest[q]; bi = wbidx[q]; }
        st_scal(&amg[b], (float)bi);
      }
    }
    GBL;
  }
  #undef GBD
  #undef GBL
}

} // namespace

// ---------------------------------------------------------------- host
extern "C" void kernel_launch(void* const* d_in, const int* in_sizes, int n_in,
                              void* d_out, int out_size, void* d_ws, size_t ws_size,
                              hipStream_t stream)
{
  const float* x     = (const float*)d_in[0];
  const float* wih_f = (const float*)d_in[2];
  const float* whh_f = (const float*)d_in[3];
  const float* bih_f = (const float*)d_in[4];
  const float* bhh_f = (const float*)d_in[5];
  const float* wih_b = (const float*)d_in[6];
  const float* whh_b = (const float*)d_in[7];
  const float* bih_b = (const float*)d_in[8];
  const float* bhh_b = (const float*)d_in[9];
  const float* w_mu  = (const float*)d_in[10];
  const float* b_mu  = (const float*)d_in[11];
  const float* w_init= (const float*)d_in[14];
  const float* b_init= (const float*)d_in[15];
  const float* w_ih0 = (const float*)d_in[16];
  const float* w_hh0 = (const float*)d_in[17];
  const float* b_ih0 = (const float*)d_in[18];
  const float* b_hh0 = (const float*)d_in[19];
  const float* w_ih1 = (const float*)d_in[20];
  const float* w_hh1 = (const float*)d_in[21];
  const float* b_ih1 = (const float*)d_in[22];
  const float* b_hh1 = (const float*)d_in[23];
  const float* w_ih2 = (const float*)d_in[24];
  const float* w_hh2 = (const float*)d_in[25];
  const float* b_ih2 = (const float*)d_in[26];
  const float* b_hh2 = (const float*)d_in[27];
  const float* w_out = (const float*)d_in[28];
  const float* b_out = (const float*)d_in[29];
  float* dout = (float*)d_out;

  float* ws = (float*)d_ws;
  float* wihfP = ws; ws += (size_t)3 * cH * WSTR;     // 4.9 MB
  float* wihbP = ws; ws += (size_t)3 * cH * WSTR;     // 4.9 MB
  float* wsc   = ws; ws += (size_t)3 * cH * 96;       // 1.2 MB
  float* gi0z  = ws; ws += (size_t)3 * cH * 64;       // 0.8 MB
  float* hfA = ws; ws += cB * cH;  float* hfB = ws; ws += cB * cH;
  float* hbA = ws; ws += cB * cH;  float* hbB = ws; ws += cB * cH;
  float* h0A = ws; ws += cB * cH;  float* h0B = ws; ws += cB * cH;
  float* h1A = ws; ws += cB * cH;  float* h1B = ws; ws += cB * cH;
  float* h2A = ws; ws += cB * cH;  float* h2B = ws; ws += cB * cH;
  float* zbuf = ws; ws += cB * cZ;
  float* amg  = ws; ws += cB;
  ws = (float*)(((uintptr_t)ws + 255) & ~(uintptr_t)255);
  unsigned* barE = (unsigned*)ws;  ws += 2048;  // 4 domains x 512
  unsigned* barD = (unsigned*)ws;  ws += 2048;  // prologue 256-dom + 2 loop domains

  init_kernel<<<256, 256, 0, stream>>>(hfA, hbA, dout + (size_t)cB * cT * cPF, barE, barD);
  pad_wih_kernel<<<512, 256, 0, stream>>>(wih_f, wihfP);
  pad_wih_kernel<<<512, 256, 0, stream>>>(wih_b, wihbP);
  pad_wsc_kernel<<<512, 256, 0, stream>>>(w_ih0, wsc);

  enc_persist<<<256, 512, 0, stream>>>(
      x,
      wihfP, whh_f, bih_f, bhh_f,
      wihbP, whh_b, bih_b, bhh_b,
      hfA, hfB, hbA, hbB, barE);

  dec_persist<<<256, 512, 0, stream>>>(
      x, hfA, hbA,
      w_mu, b_mu, w_init, b_init,
      w_ih0, wsc, w_hh0, b_ih0, b_hh0,
      w_ih1, w_hh1, b_ih1, b_hh1,
      w_ih2, w_hh2, b_ih2, b_hh2,
      w_out, b_out,
      h0A, h0B, h1A, h1B, h2A, h2B,
      gi0z, zbuf, amg, dout, barD);
}